// Round 3
// baseline (71.648 us; speedup 1.0000x reference)
//
#include <hip/hip_runtime.h>

// Problem constants (fixed by the reference):
//   B=8, N=256, IN_F=64, OUT_F=64, IN_E=32, OUT_E=64
#define BB    8
#define NN    256
#define INF   64
#define OUTF  64
#define INE   32

using f4     = __attribute__((ext_vector_type(4))) float;
using f32x4  = __attribute__((ext_vector_type(4))) float;
using bf16x8 = __attribute__((ext_vector_type(8))) short;  // 8 bf16 = 4 VGPRs

// Device-global scratch (no ws_size dependence). All fully overwritten each
// call before use (deterministic).
__device__ float          g_node_x[BB * NN * OUTF];   // emb_node@W_node + b (pre-relu)
__device__ float          g_relu_sx[BB * NN * OUTF];  // relu(emb_node@W_nodes + b)
__device__ unsigned short g_wtb[OUTF * INE];          // W_edge^T as bf16, [f][k]

// f32 -> bf16 round-to-nearest-even.
static __device__ __forceinline__ unsigned short f2bf(float x) {
    unsigned u = __builtin_bit_cast(unsigned, x);
    u += 0x7fffu + ((u >> 16) & 1u);
    return (unsigned short)(u >> 16);
}

// ---------------------------------------------------------------------------
// Kernel 1: node projections (fp32 VALU — tiny) + one-time W_edge^T bf16 prep.
// ---------------------------------------------------------------------------
__global__ __launch_bounds__(256) void node_proj(
    const float* __restrict__ emb_node,  // [B*N, 64]
    const float* __restrict__ W1, const float* __restrict__ b1,
    const float* __restrict__ W2, const float* __restrict__ b2,
    const float* __restrict__ W_edge)    // [32, 64]
{
    __shared__ float sW1[64][64];
    __shared__ float sW2[64][64];
    __shared__ float sE[4][64];

    const int tid = threadIdx.x;

    // Block 0 additionally preps W_edge^T in bf16 (2 KB) for edge_agg.
    if (blockIdx.x == 0) {
        const int f  = tid >> 2;
        const int k0 = (tid & 3) * 8;
#pragma unroll
        for (int j = 0; j < 8; ++j)
            g_wtb[f * INE + k0 + j] = f2bf(W_edge[(k0 + j) * OUTF + f]);
    }

    const f4* w1v = (const f4*)W1;
    const f4* w2v = (const f4*)W2;
    f4* s1 = (f4*)&sW1[0][0];
    f4* s2 = (f4*)&sW2[0][0];
#pragma unroll
    for (int i = 0; i < 4; ++i) {
        s1[tid + i * 256] = w1v[tid + i * 256];
        s2[tid + i * 256] = w2v[tid + i * 256];
    }
    const int row0 = blockIdx.x * 4;
    if (tid < 64) ((f4*)&sE[0][0])[tid] = ((const f4*)(emb_node + row0 * 64))[tid];
    __syncthreads();

    const int s = tid >> 6;    // row within block (0..3)
    const int f = tid & 63;    // output feature
    float a1 = b1[f];
    float a2 = b2[f];
#pragma unroll
    for (int k = 0; k < 64; ++k) {
        const float e = sE[s][k];              // broadcast read
        a1 = fmaf(e, sW1[k][f], a1);
        a2 = fmaf(e, sW2[k][f], a2);
    }
    const int row = row0 + s;
    g_node_x[row * 64 + f]  = a1;              // pre-relu (used inside einsum)
    g_relu_sx[row * 64 + f] = fmaxf(a2, 0.f);
}

// ---------------------------------------------------------------------------
// Kernel 2: per (b,n) block, 8 waves, NO LDS staging.
// MFMA with SWAPPED operands: D[f][m] = sum_k W^T[f,k] * E[m,k].
//   A-frag = W^T  : row=lane&15 (f), k=(lane>>4)*8+i  -> 16B contiguous in g_wtb
//   B-frag = E^T  : col=lane&15 (m), k=(lane>>4)*8+i  -> 16B contiguous rows of
//                   emb_edge, loaded DIRECTLY from global (2 dwordx4/lane,
//                   wave footprint = 16 full rows = 2KB dense)
//   C/D   : col=lane&15 (m), row=(lane>>4)*4+reg (f) -> each lane holds 4
//           CONSECUTIVE f for one m  => f4 stores / f4 node_x loads / f4 bias.
// Wave w owns m in [32w, 32w+32): 2 m-tiles x 4 f-tiles = 8 MFMAs.
// Epilogue: relu f4-store edge_out; agg += A[m]*edge*node_x (f4);
// shfl_xor over lane bits 0..3 (the 16 m-columns), LDS reduce over 8 waves.
// ---------------------------------------------------------------------------
__global__ __launch_bounds__(512) void edge_agg(
    const float* __restrict__ A,         // [B,N,N]
    const float* __restrict__ emb_edge,  // [B,N,N,32]
    const float* __restrict__ b_edge,    // [64]
    float* __restrict__ node_out,        // [B,N,64]
    float* __restrict__ edge_out)        // [B,N,N,64]
{
    __shared__ float sRed[8][64];        // 2 KB — only LDS in the kernel

    const int tid  = threadIdx.x;
    const int bn   = blockIdx.x;         // b*256 + n
    const int b    = bn >> 8;
    const int wave = tid >> 6;
    const int lane = tid & 63;
    const int c    = lane & 15;          // m within tile / f within W^T tile
    const int q    = lane >> 4;          // k-quad selector
    const int mbase = wave * 32;

    // ---- B fragments: E rows straight from HBM (read-once -> nontemporal) --
    bf16x8 efrag[2];
#pragma unroll
    for (int mt = 0; mt < 2; ++mt) {
        const float* rp = emb_edge + (size_t)bn * (NN * INE)
                        + (mbase + mt * 16 + c) * INE + q * 8;
        const f4 lo = __builtin_nontemporal_load((const f4*)rp);
        const f4 hi = __builtin_nontemporal_load((const f4*)rp + 1);
        bf16x8 e;
        e[0] = (short)f2bf(lo.x); e[1] = (short)f2bf(lo.y);
        e[2] = (short)f2bf(lo.z); e[3] = (short)f2bf(lo.w);
        e[4] = (short)f2bf(hi.x); e[5] = (short)f2bf(hi.y);
        e[6] = (short)f2bf(hi.z); e[7] = (short)f2bf(hi.w);
        efrag[mt] = e;
    }

    // ---- A fragments: prepped bf16 W^T, L2-hot ----
    bf16x8 wfrag[4];
#pragma unroll
    for (int ft = 0; ft < 4; ++ft)
        wfrag[ft] = *(const bf16x8*)&g_wtb[(ft * 16 + c) * INE + q * 8];

    // ---- 8 MFMAs; bias folded into C (D rows are f => per-reg bias = f4) ----
    f32x4 acc[2][4];
#pragma unroll
    for (int ft = 0; ft < 4; ++ft) {
        const f4 bias = *(const f4*)&b_edge[ft * 16 + q * 4];
#pragma unroll
        for (int mt = 0; mt < 2; ++mt)
            acc[mt][ft] = __builtin_amdgcn_mfma_f32_16x16x32_bf16(
                wfrag[ft], efrag[mt], bias, 0, 0, 0);
    }

    // ---- epilogue: f4 relu-store edge_out + weighted agg against node_x ----
    const float* Arow = A + bn * NN;
    const float* nx   = g_node_x + b * (NN * OUTF);
    float* eo = edge_out + (size_t)bn * (NN * OUTF);

    f4 agg[4];
#pragma unroll
    for (int ft = 0; ft < 4; ++ft) { agg[ft].x = 0.f; agg[ft].y = 0.f; agg[ft].z = 0.f; agg[ft].w = 0.f; }

#pragma unroll
    for (int mt = 0; mt < 2; ++mt) {
        const int   m = mbase + mt * 16 + c;
        const float a = Arow[m];                       // 64B-coalesced, L1-hot
#pragma unroll
        for (int ft = 0; ft < 4; ++ft) {
            const int fb  = ft * 16 + q * 4;
            const f4  v   = acc[mt][ft];               // pre-relu edge_x, 4 consecutive f
            const f4  nxv = *(const f4*)&nx[m * OUTF + fb];  // L2-hot f4
            f4 st;
            st.x = fmaxf(v.x, 0.f); st.y = fmaxf(v.y, 0.f);
            st.z = fmaxf(v.z, 0.f); st.w = fmaxf(v.w, 0.f);
            *(f4*)&eo[(size_t)m * OUTF + fb] = st;     // f4 store, L2 merges lines
            agg[ft].x = fmaf(a * v.x, nxv.x, agg[ft].x);
            agg[ft].y = fmaf(a * v.y, nxv.y, agg[ft].y);
            agg[ft].z = fmaf(a * v.z, nxv.z, agg[ft].z);
            agg[ft].w = fmaf(a * v.w, nxv.w, agg[ft].w);
        }
    }

    // ---- reduce over the 16 m-columns (lane bits 0..3) ----
#pragma unroll
    for (int ft = 0; ft < 4; ++ft) {
#pragma unroll
        for (int s = 1; s < 16; s <<= 1) {
            agg[ft].x += __shfl_xor(agg[ft].x, s);
            agg[ft].y += __shfl_xor(agg[ft].y, s);
            agg[ft].z += __shfl_xor(agg[ft].z, s);
            agg[ft].w += __shfl_xor(agg[ft].w, s);
        }
    }
    if (c == 0) {                        // 4 lanes/wave write 64 floats
#pragma unroll
        for (int ft = 0; ft < 4; ++ft)
            *(f4*)&sRed[wave][ft * 16 + q * 4] = agg[ft];
    }
    __syncthreads();

    // ---- reduce across 8 waves, add relu(node_sx), store node_out ----
    if (tid < 64) {
        float s = 0.f;
#pragma unroll
        for (int w = 0; w < 8; ++w) s += sRed[w][tid];
        node_out[bn * OUTF + tid] = fmaxf(s, 0.f) + g_relu_sx[bn * OUTF + tid];
    }
}

// ---------------------------------------------------------------------------
extern "C" void kernel_launch(void* const* d_in, const int* in_sizes, int n_in,
                              void* d_out, int out_size, void* d_ws, size_t ws_size,
                              hipStream_t stream) {
    const float* A        = (const float*)d_in[0];
    const float* emb_node = (const float*)d_in[1];
    const float* emb_edge = (const float*)d_in[2];
    const float* W_node   = (const float*)d_in[3];
    const float* b_node   = (const float*)d_in[4];
    const float* W_nodes  = (const float*)d_in[5];
    const float* b_nodes  = (const float*)d_in[6];
    const float* W_edge   = (const float*)d_in[7];
    const float* b_edge   = (const float*)d_in[8];

    float* node_out = (float*)d_out;                 // [8,256,64]
    float* edge_out = node_out + BB * NN * OUTF;     // [8,256,256,64]

    node_proj<<<(BB * NN) / 4, 256, 0, stream>>>(emb_node, W_node, b_node,
                                                 W_nodes, b_nodes, W_edge);
    edge_agg<<<BB * NN, 512, 0, stream>>>(A, emb_edge, b_edge, node_out, edge_out);
}

// Round 4
// 66.246 us; speedup vs baseline: 1.0815x; 1.0815x over previous
//
#include <hip/hip_runtime.h>

// Problem constants (fixed by the reference):
//   B=8, N=256, IN_F=64, OUT_F=64, IN_E=32, OUT_E=64
#define BB    8
#define NN    256
#define OUTF  64
#define INE   32

using f4     = __attribute__((ext_vector_type(4))) float;
using f32x4  = __attribute__((ext_vector_type(4))) float;
using bf16x8 = __attribute__((ext_vector_type(8))) short;          // 8 bf16 = 4 VGPRs
using us4    = __attribute__((ext_vector_type(4))) unsigned short; // 8 B

// Device-global scratch (no ws_size dependence); fully overwritten every call.
__device__ float          g_node_x[BB * NN * OUTF];   // emb_node@W_node + b (pre-relu)
__device__ float          g_relu_sx[BB * NN * OUTF];  // relu(emb_node@W_nodes + b)
__device__ unsigned short g_wtb[OUTF * INE];          // W_edge^T as bf16, [f][k]

// f32 -> bf16 round-to-nearest-even.
static __device__ __forceinline__ unsigned short f2bf(float x) {
    unsigned u = __builtin_bit_cast(unsigned, x);
    u += 0x7fffu + ((u >> 16) & 1u);
    return (unsigned short)(u >> 16);
}

// ---------------------------------------------------------------------------
// Kernel 1: node projections (fp32 VALU — tiny) + one-time W_edge^T bf16 prep.
// ---------------------------------------------------------------------------
__global__ __launch_bounds__(256) void node_proj(
    const float* __restrict__ emb_node,  // [B*N, 64]
    const float* __restrict__ W1, const float* __restrict__ b1,
    const float* __restrict__ W2, const float* __restrict__ b2,
    const float* __restrict__ W_edge)    // [32, 64]
{
    __shared__ float sW1[64][64];
    __shared__ float sW2[64][64];
    __shared__ float sE[4][64];

    const int tid = threadIdx.x;

    if (blockIdx.x == 0) {               // prep W_edge^T bf16 (2 KB)
        const int f  = tid >> 2;
        const int k0 = (tid & 3) * 8;
#pragma unroll
        for (int j = 0; j < 8; ++j)
            g_wtb[f * INE + k0 + j] = f2bf(W_edge[(k0 + j) * OUTF + f]);
    }

    const f4* w1v = (const f4*)W1;
    const f4* w2v = (const f4*)W2;
    f4* s1 = (f4*)&sW1[0][0];
    f4* s2 = (f4*)&sW2[0][0];
#pragma unroll
    for (int i = 0; i < 4; ++i) {
        s1[tid + i * 256] = w1v[tid + i * 256];
        s2[tid + i * 256] = w2v[tid + i * 256];
    }
    const int row0 = blockIdx.x * 4;
    if (tid < 64) ((f4*)&sE[0][0])[tid] = ((const f4*)(emb_node + row0 * 64))[tid];
    __syncthreads();

    const int s = tid >> 6;
    const int f = tid & 63;
    float a1 = b1[f];
    float a2 = b2[f];
#pragma unroll
    for (int k = 0; k < 64; ++k) {
        const float e = sE[s][k];
        a1 = fmaf(e, sW1[k][f], a1);
        a2 = fmaf(e, sW2[k][f], a2);
    }
    const int row = row0 + s;
    g_node_x[row * 64 + f]  = a1;
    g_relu_sx[row * 64 + f] = fmaxf(a2, 0.f);
}

// ---------------------------------------------------------------------------
// Kernel 2: per (b,n) block, 256 threads = 4 waves, ~5 blocks/CU.
// Staging (R1-proven pattern): consecutive-tid nt f4 loads -> bf16 LDS,
// row stride 40 shorts (80 B): staging b64 writes balanced 4/bank; frag
// ds_read_b128 uniform 8/bank (conflict-free minimum for b128).
// MFMA swapped operands (R3-verified): D[f][m] = sum_k W^T[f,k] E[m,k];
// lane(c=lane&15 -> m, q=lane>>4): A-frag W^T[(ft*16+c)][q*8..], B-frag
// E[m][q*8..], C/D reg r -> f = ft*16 + q*4 + r  => f4 epilogue everywhere.
// Per-mt fused epilogue keeps acc transient (VGPR ~90 -> 4 waves/SIMD).
// Wave w owns m in [64w, 64w+64): 4 mt x 4 ft MFMAs.
// ---------------------------------------------------------------------------
__global__ __launch_bounds__(256, 4) void edge_agg(
    const float* __restrict__ A,         // [B,N,N]
    const float* __restrict__ emb_edge,  // [B,N,N,32]
    const float* __restrict__ b_edge,    // [64]
    float* __restrict__ node_out,        // [B,N,64]
    float* __restrict__ edge_out)        // [B,N,N,64]
{
    __shared__ unsigned short sEb[256 * 40]; // 20 KB bf16 E tile, 8-short row pad
    __shared__ float sRed[4][64];            // 1 KB wave partials

    const int tid  = threadIdx.x;
    const int bn   = blockIdx.x;             // b*256 + n
    const int b    = bn >> 8;
    const int wave = tid >> 6;
    const int lane = tid & 63;
    const int c    = lane & 15;              // m within 16-tile / f-row of W^T
    const int q    = lane >> 4;              // k-quad & f-quad selector

    // ---- L2-hot fragments first (independent loads, overlap with staging) --
    bf16x8 wfrag[4];
    f4     bias[4];
#pragma unroll
    for (int ft = 0; ft < 4; ++ft) {
        wfrag[ft] = *(const bf16x8*)&g_wtb[(ft * 16 + c) * INE + q * 8];
        bias[ft]  = *(const f4*)&b_edge[ft * 16 + q * 4];
    }

    // ---- stage E -> bf16 LDS: 2048 f4 chunks, 8 per thread, wave-dense ----
    const f4* embv = (const f4*)(emb_edge + (size_t)bn * (NN * INE));
#pragma unroll
    for (int it = 0; it < 8; ++it) {
        const int i = tid + it * 256;        // row = i>>3, k-quad = i&7
        const f4 v = __builtin_nontemporal_load(embv + i);
        us4 h;
        h.x = f2bf(v.x); h.y = f2bf(v.y); h.z = f2bf(v.z); h.w = f2bf(v.w);
        *(us4*)&sEb[(i >> 3) * 40 + (i & 7) * 4] = h;
    }
    __syncthreads();

    const int    wbase = wave * 64;
    const float* Arow  = A + bn * NN;
    const float* nx    = g_node_x + b * (NN * OUTF);
    float*       eo    = edge_out + (size_t)bn * (NN * OUTF);

    f4 agg[4];
#pragma unroll
    for (int ft = 0; ft < 4; ++ft) { agg[ft].x = 0.f; agg[ft].y = 0.f; agg[ft].z = 0.f; agg[ft].w = 0.f; }

#pragma unroll
    for (int mt = 0; mt < 4; ++mt) {
        const int   m     = wbase + mt * 16 + c;
        const float a     = Arow[m];                               // L2/L1-hot
        const bf16x8 efrag = *(const bf16x8*)&sEb[m * 40 + q * 8]; // b128, balanced

        f32x4 acc[4];
#pragma unroll
        for (int ft = 0; ft < 4; ++ft)
            acc[ft] = __builtin_amdgcn_mfma_f32_16x16x32_bf16(
                wfrag[ft], efrag, bias[ft], 0, 0, 0);

        // fused epilogue for this mt: relu f4 nt store + weighted agg
#pragma unroll
        for (int ft = 0; ft < 4; ++ft) {
            const int fb  = ft * 16 + q * 4;
            const f4  v   = acc[ft];                        // pre-relu edge_x
            const f4  nxv = *(const f4*)&nx[m * OUTF + fb]; // L2-hot
            f4 st;
            st.x = fmaxf(v.x, 0.f); st.y = fmaxf(v.y, 0.f);
            st.z = fmaxf(v.z, 0.f); st.w = fmaxf(v.w, 0.f);
            __builtin_nontemporal_store(st, (f4*)&eo[(size_t)m * OUTF + fb]);
            agg[ft].x = fmaf(a * v.x, nxv.x, agg[ft].x);
            agg[ft].y = fmaf(a * v.y, nxv.y, agg[ft].y);
            agg[ft].z = fmaf(a * v.z, nxv.z, agg[ft].z);
            agg[ft].w = fmaf(a * v.w, nxv.w, agg[ft].w);
        }
    }

    // ---- reduce over the 16 m-columns (lane bits 0..3 == c) ----
#pragma unroll
    for (int ft = 0; ft < 4; ++ft) {
#pragma unroll
        for (int s = 1; s < 16; s <<= 1) {
            agg[ft].x += __shfl_xor(agg[ft].x, s);
            agg[ft].y += __shfl_xor(agg[ft].y, s);
            agg[ft].z += __shfl_xor(agg[ft].z, s);
            agg[ft].w += __shfl_xor(agg[ft].w, s);
        }
    }
    if (c == 0) {
#pragma unroll
        for (int ft = 0; ft < 4; ++ft)
            *(f4*)&sRed[wave][ft * 16 + q * 4] = agg[ft];
    }
    __syncthreads();

    // ---- reduce across 4 waves, add relu(node_sx), store node_out ----
    if (tid < 64) {
        float s = sRed[0][tid] + sRed[1][tid] + sRed[2][tid] + sRed[3][tid];
        node_out[bn * OUTF + tid] = fmaxf(s, 0.f) + g_relu_sx[bn * OUTF + tid];
    }
}

// ---------------------------------------------------------------------------
extern "C" void kernel_launch(void* const* d_in, const int* in_sizes, int n_in,
                              void* d_out, int out_size, void* d_ws, size_t ws_size,
                              hipStream_t stream) {
    const float* A        = (const float*)d_in[0];
    const float* emb_node = (const float*)d_in[1];
    const float* emb_edge = (const float*)d_in[2];
    const float* W_node   = (const float*)d_in[3];
    const float* b_node   = (const float*)d_in[4];
    const float* W_nodes  = (const float*)d_in[5];
    const float* b_nodes  = (const float*)d_in[6];
    const float* W_edge   = (const float*)d_in[7];
    const float* b_edge   = (const float*)d_in[8];

    float* node_out = (float*)d_out;                 // [8,256,64]
    float* edge_out = node_out + BB * NN * OUTF;     // [8,256,256,64]

    node_proj<<<(BB * NN) / 4, 256, 0, stream>>>(emb_node, W_node, b_node,
                                                 W_nodes, b_nodes, W_edge);
    edge_agg<<<BB * NN, 256, 0, stream>>>(A, emb_edge, b_edge, node_out, edge_out);
}